// Round 1
// baseline (1096.606 us; speedup 1.0000x reference)
//
#include <hip/hip_runtime.h>
#include <math.h>

#define GK 602
#define GH 128
#define GC 41

// ---------------- CSR build ----------------

__global__ void k_hist(const int* __restrict__ dst, int* __restrict__ counts, int E) {
    int e = blockIdx.x * 256 + threadIdx.x;
    if (e < E) atomicAdd(&counts[dst[e]], 1);
}

// exclusive scan of counts[0..n-1] -> row_ptr, 1024 elems/block
__global__ void k_scan_a(const int* __restrict__ counts, int* __restrict__ row_ptr,
                         int* __restrict__ bsum, int n) {
    __shared__ int svals[256];
    __shared__ int soffs[256];
    int t = threadIdx.x;
    int base = blockIdx.x * 1024 + t * 4;
    int v[4];
    int s = 0;
#pragma unroll
    for (int j = 0; j < 4; ++j) {
        int idx = base + j;
        v[j] = (idx < n) ? counts[idx] : 0;
        s += v[j];
    }
    svals[t] = s;
    __syncthreads();
    if (t == 0) {
        int acc = 0;
        for (int i = 0; i < 256; ++i) { int tmp = svals[i]; soffs[i] = acc; acc += tmp; }
        bsum[blockIdx.x] = acc;
    }
    __syncthreads();
    int off = soffs[t];
#pragma unroll
    for (int j = 0; j < 4; ++j) {
        int idx = base + j;
        if (idx < n) row_ptr[idx] = off;
        off += v[j];
    }
}

__global__ void k_scan_b(int* __restrict__ bsum, int nb) {
    if (threadIdx.x == 0 && blockIdx.x == 0) {
        int acc = 0;
        for (int i = 0; i < nb; ++i) { int t = bsum[i]; bsum[i] = acc; acc += t; }
    }
}

__global__ void k_scan_c(int* __restrict__ row_ptr, const int* __restrict__ bsum, int n, int E) {
    int i = blockIdx.x * 256 + threadIdx.x;
    if (i < n) row_ptr[i] += bsum[i >> 10];
    if (i == 0) row_ptr[n] = E;
}

__global__ void k_dinv_cursor(const int* __restrict__ counts, const int* __restrict__ row_ptr,
                              float* __restrict__ dinv, int* __restrict__ cursor, int n) {
    int i = blockIdx.x * 256 + threadIdx.x;
    if (i < n) {
        dinv[i] = rsqrtf((float)(counts[i] + 1));  // +1 self-loop; always > 0
        cursor[i] = row_ptr[i];
    }
}

__global__ void k_fill(const int* __restrict__ src, const int* __restrict__ dst,
                       int* __restrict__ cursor, int* __restrict__ col, int E) {
    int e = blockIdx.x * 256 + threadIdx.x;
    if (e < E) {
        int d = dst[e];
        int p = atomicAdd(&cursor[d], 1);
        col[p] = src[e];
    }
}

// ---------------- GEMM1: X(M x 602) @ W1(602 x 128) -> Y(M x 128) ----------------
// 64x128 tile / block (256 thr), K-tile 16, micro-tile 8x4.

__global__ __launch_bounds__(256) void k_gemm1(const float* __restrict__ X,
                                               const float* __restrict__ W,
                                               float* __restrict__ Y, int M) {
    __shared__ float xs[16][64];
    __shared__ float ws[16][128];
    const int K = GK;
    int tid = threadIdx.x;
    int row0 = blockIdx.x * 64;
    int tx = tid & 31;
    int ty = tid >> 5;
    float acc[8][4];
#pragma unroll
    for (int r = 0; r < 8; ++r)
#pragma unroll
        for (int c = 0; c < 4; ++c) acc[r][c] = 0.f;

    int xr = tid >> 2;          // 0..63 staging row
    int xk = (tid & 3) * 4;     // 4 consecutive k per thread
    int wkk = tid >> 5;         // 0..7
    int wc = (tid & 31) * 4;
    int grow = row0 + xr;
    const float* xrow = X + (size_t)grow * K;

    for (int k0 = 0; k0 < K; k0 += 16) {
#pragma unroll
        for (int j = 0; j < 4; ++j) {
            int kk = xk + j;
            int gk = k0 + kk;
            float v = 0.f;
            if (grow < M && gk < K) v = xrow[gk];
            xs[kk][xr] = v;
        }
#pragma unroll
        for (int h = 0; h < 2; ++h) {
            int kk = wkk + 8 * h;
            int gk = k0 + kk;
            float4 v = make_float4(0.f, 0.f, 0.f, 0.f);
            if (gk < K) v = *(const float4*)&W[gk * GH + wc];
            *(float4*)&ws[kk][wc] = v;
        }
        __syncthreads();
#pragma unroll
        for (int kk = 0; kk < 16; ++kk) {
            float4 a0 = *(const float4*)&xs[kk][ty * 8];
            float4 a1 = *(const float4*)&xs[kk][ty * 8 + 4];
            float4 bv = *(const float4*)&ws[kk][tx * 4];
            float a[8] = {a0.x, a0.y, a0.z, a0.w, a1.x, a1.y, a1.z, a1.w};
            float b[4] = {bv.x, bv.y, bv.z, bv.w};
#pragma unroll
            for (int r = 0; r < 8; ++r)
#pragma unroll
                for (int c = 0; c < 4; ++c)
                    acc[r][c] = fmaf(a[r], b[c], acc[r][c]);
        }
        __syncthreads();
    }
#pragma unroll
    for (int r = 0; r < 8; ++r) {
        int orow = row0 + ty * 8 + r;
        if (orow < M) {
            float4 v = make_float4(acc[r][0], acc[r][1], acc[r][2], acc[r][3]);
            *(float4*)&Y[(size_t)orow * GH + tx * 4] = v;
        }
    }
}

// ---------------- CSR gather-aggregate (128-wide), 1 wave per dst node ----------------

__global__ __launch_bounds__(256) void k_agg(const float* __restrict__ H, float* __restrict__ O,
                                             const int* __restrict__ row_ptr,
                                             const int* __restrict__ col,
                                             const float* __restrict__ dinv,
                                             const float* __restrict__ bias,
                                             int n, int relu) {
    int wave = threadIdx.x >> 6;
    int lane = threadIdx.x & 63;
    int dst = blockIdx.x * 4 + wave;
    if (dst >= n) return;
    float dd = dinv[dst];
    int beg = row_ptr[dst], end = row_ptr[dst + 1];
    float a0 = dd * dd * H[dst * GH + lane];
    float a1 = dd * dd * H[dst * GH + 64 + lane];
    for (int e = beg; e < end; ++e) {
        int s = col[e];
        float w = dinv[s] * dd;
        a0 = fmaf(w, H[s * GH + lane], a0);
        a1 = fmaf(w, H[s * GH + 64 + lane], a1);
    }
    if (bias) { a0 += bias[lane]; a1 += bias[64 + lane]; }
    if (relu) { a0 = fmaxf(a0, 0.f); a1 = fmaxf(a1, 0.f); }
    O[dst * GH + lane] = a0;
    O[dst * GH + 64 + lane] = a1;
}

// ---------------- GEMM2 (T: M x 128 @ W2: 128 x 41) + bias + log_softmax ----------------

__global__ __launch_bounds__(256) void k_gemm2(const float* __restrict__ T,
                                               const float* __restrict__ W2,
                                               const float* __restrict__ b2,
                                               float* __restrict__ out, int n) {
    __shared__ float ws[128][44];  // padded to 44 (16B-aligned rows)
    for (int i = threadIdx.x; i < 128 * 44; i += 256) {
        int k = i / 44;
        int c = i - k * 44;
        ws[k][c] = (c < GC) ? W2[k * GC + c] : 0.f;
    }
    __syncthreads();
    int r = blockIdx.x * 256 + threadIdx.x;
    if (r >= n) return;
    float acc[44];
#pragma unroll
    for (int c = 0; c < 44; ++c) acc[c] = 0.f;
    const float4* t4 = (const float4*)(T + (size_t)r * GH);
#pragma unroll 4
    for (int kq = 0; kq < 32; ++kq) {
        float4 xv = t4[kq];
#pragma unroll
        for (int j = 0; j < 11; ++j) {
            float4 w0 = *(const float4*)&ws[4 * kq + 0][4 * j];
            float4 w1 = *(const float4*)&ws[4 * kq + 1][4 * j];
            float4 w2 = *(const float4*)&ws[4 * kq + 2][4 * j];
            float4 w3 = *(const float4*)&ws[4 * kq + 3][4 * j];
            acc[4 * j + 0] += xv.x * w0.x + xv.y * w1.x + xv.z * w2.x + xv.w * w3.x;
            acc[4 * j + 1] += xv.x * w0.y + xv.y * w1.y + xv.z * w2.y + xv.w * w3.y;
            acc[4 * j + 2] += xv.x * w0.z + xv.y * w1.z + xv.z * w2.z + xv.w * w3.z;
            acc[4 * j + 3] += xv.x * w0.w + xv.y * w1.w + xv.z * w2.w + xv.w * w3.w;
        }
    }
    float vals[GC];
    float m = -1e30f;
#pragma unroll
    for (int c = 0; c < GC; ++c) {
        vals[c] = acc[c] + b2[c];
        m = fmaxf(m, vals[c]);
    }
    float s = 0.f;
#pragma unroll
    for (int c = 0; c < GC; ++c) s += __expf(vals[c] - m);
    float lse = m + __logf(s);
#pragma unroll
    for (int c = 0; c < GC; ++c) out[(size_t)r * GC + c] = vals[c] - lse;
}

// ---------------- launch ----------------

static inline size_t alignup256(size_t x) { return (x + 255) & ~(size_t)255; }

extern "C" void kernel_launch(void* const* d_in, const int* in_sizes, int n_in,
                              void* d_out, int out_size, void* d_ws, size_t ws_size,
                              hipStream_t stream) {
    const float* x  = (const float*)d_in[0];
    const int*   ei = (const int*)d_in[1];
    const float* W1 = (const float*)d_in[2];
    const float* b1 = (const float*)d_in[3];
    const float* W2 = (const float*)d_in[4];
    const float* b2 = (const float*)d_in[5];
    float* out = (float*)d_out;

    const int n = in_sizes[0] / GK;   // 100000
    const int E = in_sizes[1] / 2;    // 1600000
    const int* src = ei;
    const int* dst = ei + E;

    char* w = (char*)d_ws;
    char* p;
    p = w; w += alignup256((size_t)n * 4);        float* dinv  = (float*)p;
    p = w; w += alignup256((size_t)n * 4);        int* counts  = (int*)p;
    p = w; w += alignup256((size_t)n * 4);        int* cursor  = (int*)p;
    p = w; w += alignup256((size_t)(n + 1) * 4);  int* row_ptr = (int*)p;
    p = w; w += alignup256(1024 * 4);             int* bsum    = (int*)p;
    p = w; w += alignup256((size_t)E * 4);        int* col     = (int*)p;
    p = w; w += alignup256((size_t)n * GH * 4);   float* bufA  = (float*)p;
    p = w; w += alignup256((size_t)n * GH * 4);   float* bufB  = (float*)p;

    hipMemsetAsync(counts, 0, (size_t)n * 4, stream);

    int gE = (E + 255) / 256;
    int gN = (n + 255) / 256;
    int nb = (n + 1023) / 1024;

    k_hist<<<gE, 256, 0, stream>>>(dst, counts, E);
    k_scan_a<<<nb, 256, 0, stream>>>(counts, row_ptr, bsum, n);
    k_scan_b<<<1, 64, 0, stream>>>(bsum, nb);
    k_scan_c<<<gN, 256, 0, stream>>>(row_ptr, bsum, n, E);
    k_dinv_cursor<<<gN, 256, 0, stream>>>(counts, row_ptr, dinv, cursor, n);
    k_fill<<<gE, 256, 0, stream>>>(src, dst, cursor, col, E);

    k_gemm1<<<(n + 63) / 64, 256, 0, stream>>>(x, W1, bufA, n);
    k_agg<<<(n + 3) / 4, 256, 0, stream>>>(bufA, bufB, row_ptr, col, dinv, b1, n, 1);
    k_agg<<<(n + 3) / 4, 256, 0, stream>>>(bufB, bufA, row_ptr, col, dinv, (const float*)nullptr, n, 0);
    k_gemm2<<<gN, 256, 0, stream>>>(bufA, W2, b2, out, n);
}

// Round 2
// 928.451 us; speedup vs baseline: 1.1811x; 1.1811x over previous
//
#include <hip/hip_runtime.h>
#include <math.h>

#define GK 602
#define GH 128
#define GC 41
#define KPAD 608   // 19 k-tiles of 32
#define GS 40      // LDS row stride in bf16 elems (80 B, 16B-aligned)

typedef __bf16 bf16x8 __attribute__((ext_vector_type(8)));
typedef __bf16 bf16x4 __attribute__((ext_vector_type(4)));
typedef float f32x16 __attribute__((ext_vector_type(16)));

__device__ __forceinline__ unsigned short f2bf(float f) {
    __bf16 b = (__bf16)f;
    return __builtin_bit_cast(unsigned short, b);
}
__device__ __forceinline__ float bflo(unsigned int u) { return __uint_as_float(u << 16); }
__device__ __forceinline__ float bfhi(unsigned int u) { return __uint_as_float(u & 0xffff0000u); }

// ---------------- CSR build ----------------

__global__ void k_hist(const int* __restrict__ dst, int* __restrict__ counts, int E) {
    int e = blockIdx.x * 256 + threadIdx.x;
    if (e < E) atomicAdd(&counts[dst[e]], 1);
}

__global__ void k_scan_a(const int* __restrict__ counts, int* __restrict__ row_ptr,
                         int* __restrict__ bsum, int n) {
    __shared__ int svals[256];
    __shared__ int soffs[256];
    int t = threadIdx.x;
    int base = blockIdx.x * 1024 + t * 4;
    int v[4];
    int s = 0;
#pragma unroll
    for (int j = 0; j < 4; ++j) {
        int idx = base + j;
        v[j] = (idx < n) ? counts[idx] : 0;
        s += v[j];
    }
    svals[t] = s;
    __syncthreads();
    if (t == 0) {
        int acc = 0;
        for (int i = 0; i < 256; ++i) { int tmp = svals[i]; soffs[i] = acc; acc += tmp; }
        bsum[blockIdx.x] = acc;
    }
    __syncthreads();
    int off = soffs[t];
#pragma unroll
    for (int j = 0; j < 4; ++j) {
        int idx = base + j;
        if (idx < n) row_ptr[idx] = off;
        off += v[j];
    }
}

__global__ void k_scan_b(int* __restrict__ bsum, int nb) {
    if (threadIdx.x == 0 && blockIdx.x == 0) {
        int acc = 0;
        for (int i = 0; i < nb; ++i) { int t = bsum[i]; bsum[i] = acc; acc += t; }
    }
}

__global__ void k_scan_c(int* __restrict__ row_ptr, const int* __restrict__ bsum, int n, int E) {
    int i = blockIdx.x * 256 + threadIdx.x;
    if (i < n) row_ptr[i] += bsum[i >> 10];
    if (i == 0) row_ptr[n] = E;
}

__global__ void k_dinv_cursor(const int* __restrict__ counts, const int* __restrict__ row_ptr,
                              float* __restrict__ dinv, int* __restrict__ cursor, int n) {
    int i = blockIdx.x * 256 + threadIdx.x;
    if (i < n) {
        dinv[i] = rsqrtf((float)(counts[i] + 1));
        cursor[i] = row_ptr[i];
    }
}

__global__ void k_fill(const int* __restrict__ src, const int* __restrict__ dst,
                       int* __restrict__ cursor, int* __restrict__ col, int E) {
    int e = blockIdx.x * 256 + threadIdx.x;
    if (e < E) {
        int d = dst[e];
        int p = atomicAdd(&cursor[d], 1);
        col[p] = src[e];
    }
}

// ---------------- W1 -> bf16 transposed+padded: W1T[n][k], n<128, k<608 ----------------

__global__ void k_prepW1(const float* __restrict__ W1, unsigned short* __restrict__ W1T) {
    int i = blockIdx.x * 256 + threadIdx.x;
    if (i >= GH * KPAD) return;
    int n = i / KPAD;
    int k = i - n * KPAD;
    float v = (k < GK) ? W1[(size_t)k * GH + n] : 0.f;
    W1T[i] = f2bf(v);
}

// ---------------- GEMM1 via MFMA bf16: X(M x 602) @ W1 -> Y bf16 (M x 128) ----------------
// 128 rows/block, 4 waves; wave w: rows 32w..32w+31, all 4 n-tiles of 32.

__global__ __launch_bounds__(256) void k_gemm1_mfma(const float* __restrict__ X,
                                                    const unsigned short* __restrict__ W1T,
                                                    unsigned short* __restrict__ Y, int M) {
    __shared__ __bf16 As[128 * GS];
    __shared__ __bf16 Bs[128 * GS];
    int tid = threadIdx.x;
    int lane = tid & 63;
    int w = tid >> 6;
    int row0 = blockIdx.x * 128;

    f32x16 acc[4];
#pragma unroll
    for (int c = 0; c < 4; ++c)
#pragma unroll
        for (int i = 0; i < 16; ++i) acc[c][i] = 0.f;

    int sr = tid >> 3;            // 0..31 staging row (A)
    int sk = (tid & 7) * 4;       // 0..28 k-offset (A), 4 floats each
    int am = 32 * w + (lane & 31);
    int kh = (lane >> 5) * 8;     // 0 or 8
    int bn = lane & 31;

    for (int k0 = 0; k0 < KPAD; k0 += 32) {
        // stage A: 128 rows x 32 k, fp32 -> bf16
#pragma unroll
        for (int p = 0; p < 4; ++p) {
            int r = sr + 32 * p;
            int gr = row0 + r;
            int gk = k0 + sk;
            float4 v = make_float4(0.f, 0.f, 0.f, 0.f);
            if (gr < M) {
                if (gk + 4 <= GK) {
                    v = *(const float4*)&X[(size_t)gr * GK + gk];
                } else {
                    float t0 = (gk + 0 < GK) ? X[(size_t)gr * GK + gk + 0] : 0.f;
                    float t1 = (gk + 1 < GK) ? X[(size_t)gr * GK + gk + 1] : 0.f;
                    float t2 = (gk + 2 < GK) ? X[(size_t)gr * GK + gk + 2] : 0.f;
                    float t3 = (gk + 3 < GK) ? X[(size_t)gr * GK + gk + 3] : 0.f;
                    v = make_float4(t0, t1, t2, t3);
                }
            }
            bf16x4 b4;
            b4[0] = (__bf16)v.x; b4[1] = (__bf16)v.y; b4[2] = (__bf16)v.z; b4[3] = (__bf16)v.w;
            *(bf16x4*)&As[r * GS + sk] = b4;
        }
        // stage B: 128 n-rows x 32 k from W1T (already bf16, padded)
#pragma unroll
        for (int s = 0; s < 2; ++s) {
            int slot = tid + 256 * s;
            int n = slot >> 2;
            int j = slot & 3;
            uint4 v = *(const uint4*)&W1T[(size_t)n * KPAD + k0 + 8 * j];
            *(uint4*)&Bs[n * GS + 8 * j] = v;
        }
        __syncthreads();
#pragma unroll
        for (int t = 0; t < 2; ++t) {
            bf16x8 af = *(const bf16x8*)&As[am * GS + 16 * t + kh];
#pragma unroll
            for (int c = 0; c < 4; ++c) {
                bf16x8 bf = *(const bf16x8*)&Bs[(32 * c + bn) * GS + 16 * t + kh];
                acc[c] = __builtin_amdgcn_mfma_f32_32x32x16_bf16(af, bf, acc[c], 0, 0, 0);
            }
        }
        __syncthreads();
    }
    // epilogue: C/D layout col=lane&31, row=(reg&3)+8*(reg>>2)+4*(lane>>5)
#pragma unroll
    for (int c = 0; c < 4; ++c) {
#pragma unroll
        for (int reg = 0; reg < 16; ++reg) {
            int rrow = (reg & 3) + 8 * (reg >> 2) + 4 * (lane >> 5);
            int grow = row0 + 32 * w + rrow;
            int gcol = 32 * c + (lane & 31);
            if (grow < M) Y[(size_t)grow * GH + gcol] = f2bf(acc[c][reg]);
        }
    }
}

// ---------------- CSR gather-aggregate, bf16 input (packed 2/uint), 1 wave/dst ----------------

__global__ __launch_bounds__(256) void k_agg1(const unsigned int* __restrict__ H,
                                              unsigned int* __restrict__ O,
                                              const int* __restrict__ row_ptr,
                                              const int* __restrict__ col,
                                              const float* __restrict__ dinv,
                                              const float* __restrict__ bias, int n) {
    int wv = threadIdx.x >> 6;
    int lane = threadIdx.x & 63;
    int d = blockIdx.x * 4 + wv;
    if (d >= n) return;
    float dd = dinv[d];
    int beg = row_ptr[d], end = row_ptr[d + 1];
    unsigned int v = H[(size_t)d * 64 + lane];
    float w0 = dd * dd;
    float a0 = w0 * bflo(v);
    float a1 = w0 * bfhi(v);
    for (int e = beg; e < end; ++e) {
        int s = col[e];
        float w = dinv[s] * dd;
        unsigned int u = H[(size_t)s * 64 + lane];
        a0 = fmaf(w, bflo(u), a0);
        a1 = fmaf(w, bfhi(u), a1);
    }
    a0 = fmaxf(a0 + bias[2 * lane], 0.f);
    a1 = fmaxf(a1 + bias[2 * lane + 1], 0.f);
    O[(size_t)d * 64 + lane] = (unsigned int)f2bf(a0) | ((unsigned int)f2bf(a1) << 16);
}

__global__ __launch_bounds__(256) void k_agg2(const unsigned int* __restrict__ H,
                                              float* __restrict__ O,
                                              const int* __restrict__ row_ptr,
                                              const int* __restrict__ col,
                                              const float* __restrict__ dinv, int n) {
    int wv = threadIdx.x >> 6;
    int lane = threadIdx.x & 63;
    int d = blockIdx.x * 4 + wv;
    if (d >= n) return;
    float dd = dinv[d];
    int beg = row_ptr[d], end = row_ptr[d + 1];
    unsigned int v = H[(size_t)d * 64 + lane];
    float w0 = dd * dd;
    float a0 = w0 * bflo(v);
    float a1 = w0 * bfhi(v);
    for (int e = beg; e < end; ++e) {
        int s = col[e];
        float w = dinv[s] * dd;
        unsigned int u = H[(size_t)s * 64 + lane];
        a0 = fmaf(w, bflo(u), a0);
        a1 = fmaf(w, bfhi(u), a1);
    }
    float2 r = make_float2(a0, a1);
    *(float2*)&O[(size_t)d * GH + 2 * lane] = r;
}

// ---------------- GEMM2 (T: M x 128 fp32 @ W2: 128 x 41) + bias + log_softmax ----------------

__global__ __launch_bounds__(256) void k_gemm2(const float* __restrict__ T,
                                               const float* __restrict__ W2,
                                               const float* __restrict__ b2,
                                               float* __restrict__ out, int n) {
    __shared__ float ws[128][44];
    for (int i = threadIdx.x; i < 128 * 44; i += 256) {
        int k = i / 44;
        int c = i - k * 44;
        ws[k][c] = (c < GC) ? W2[k * GC + c] : 0.f;
    }
    __syncthreads();
    int r = blockIdx.x * 256 + threadIdx.x;
    if (r >= n) return;
    float acc[44];
#pragma unroll
    for (int c = 0; c < 44; ++c) acc[c] = 0.f;
    const float4* t4 = (const float4*)(T + (size_t)r * GH);
#pragma unroll 4
    for (int kq = 0; kq < 32; ++kq) {
        float4 xv = t4[kq];
#pragma unroll
        for (int j = 0; j < 11; ++j) {
            float4 w0 = *(const float4*)&ws[4 * kq + 0][4 * j];
            float4 w1 = *(const float4*)&ws[4 * kq + 1][4 * j];
            float4 w2 = *(const float4*)&ws[4 * kq + 2][4 * j];
            float4 w3 = *(const float4*)&ws[4 * kq + 3][4 * j];
            acc[4 * j + 0] += xv.x * w0.x + xv.y * w1.x + xv.z * w2.x + xv.w * w3.x;
            acc[4 * j + 1] += xv.x * w0.y + xv.y * w1.y + xv.z * w2.y + xv.w * w3.y;
            acc[4 * j + 2] += xv.x * w0.z + xv.y * w1.z + xv.z * w2.z + xv.w * w3.z;
            acc[4 * j + 3] += xv.x * w0.w + xv.y * w1.w + xv.z * w2.w + xv.w * w3.w;
        }
    }
    float vals[GC];
    float m = -1e30f;
#pragma unroll
    for (int c = 0; c < GC; ++c) {
        vals[c] = acc[c] + b2[c];
        m = fmaxf(m, vals[c]);
    }
    float s = 0.f;
#pragma unroll
    for (int c = 0; c < GC; ++c) s += __expf(vals[c] - m);
    float lse = m + __logf(s);
#pragma unroll
    for (int c = 0; c < GC; ++c) out[(size_t)r * GC + c] = vals[c] - lse;
}

// ---------------- launch ----------------

static inline size_t alignup256(size_t x) { return (x + 255) & ~(size_t)255; }

extern "C" void kernel_launch(void* const* d_in, const int* in_sizes, int n_in,
                              void* d_out, int out_size, void* d_ws, size_t ws_size,
                              hipStream_t stream) {
    const float* x  = (const float*)d_in[0];
    const int*   ei = (const int*)d_in[1];
    const float* W1 = (const float*)d_in[2];
    const float* b1 = (const float*)d_in[3];
    const float* W2 = (const float*)d_in[4];
    const float* b2 = (const float*)d_in[5];
    float* out = (float*)d_out;

    const int n = in_sizes[0] / GK;   // 100000
    const int E = in_sizes[1] / 2;    // 1600000
    const int* src = ei;
    const int* dst = ei + E;

    char* w = (char*)d_ws;
    char* p;
    p = w; w += alignup256((size_t)n * 4);            float* dinv  = (float*)p;
    p = w; w += alignup256((size_t)n * 4);            int* counts  = (int*)p;
    p = w; w += alignup256((size_t)n * 4);            int* cursor  = (int*)p;
    p = w; w += alignup256((size_t)(n + 1) * 4);      int* row_ptr = (int*)p;
    p = w; w += alignup256(1024 * 4);                 int* bsum    = (int*)p;
    p = w; w += alignup256((size_t)E * 4);            int* col     = (int*)p;
    p = w; w += alignup256((size_t)GH * KPAD * 2);    unsigned short* W1T = (unsigned short*)p;
    p = w; w += alignup256((size_t)n * GH * 2);       unsigned short* bufA = (unsigned short*)p; // bf16 H1
    p = w; w += alignup256((size_t)n * GH * 2);       unsigned short* bufB = (unsigned short*)p; // bf16 relu(agg)
    p = w; w += alignup256((size_t)n * GH * 4);       float* bufC = (float*)p;                   // fp32 agg2

    hipMemsetAsync(counts, 0, (size_t)n * 4, stream);

    int gE = (E + 255) / 256;
    int gN = (n + 255) / 256;
    int nb = (n + 1023) / 1024;

    k_hist<<<gE, 256, 0, stream>>>(dst, counts, E);
    k_scan_a<<<nb, 256, 0, stream>>>(counts, row_ptr, bsum, n);
    k_scan_b<<<1, 64, 0, stream>>>(bsum, nb);
    k_scan_c<<<gN, 256, 0, stream>>>(row_ptr, bsum, n, E);
    k_dinv_cursor<<<gN, 256, 0, stream>>>(counts, row_ptr, dinv, cursor, n);
    k_fill<<<gE, 256, 0, stream>>>(src, dst, cursor, col, E);

    k_prepW1<<<(GH * KPAD + 255) / 256, 256, 0, stream>>>(W1, W1T);
    k_gemm1_mfma<<<(n + 127) / 128, 256, 0, stream>>>(x, W1T, bufA, n);
    k_agg1<<<(n + 3) / 4, 256, 0, stream>>>((const unsigned int*)bufA, (unsigned int*)bufB,
                                            row_ptr, col, dinv, b1, n);
    k_agg2<<<(n + 3) / 4, 256, 0, stream>>>((const unsigned int*)bufB, bufC,
                                            row_ptr, col, dinv, n);
    k_gemm2<<<gN, 256, 0, stream>>>(bufC, W2, b2, out, n);
}

// Round 3
// 729.739 us; speedup vs baseline: 1.5027x; 1.2723x over previous
//
#include <hip/hip_runtime.h>
#include <math.h>

#define GK 602
#define GH 128
#define GC 41
#define GCP 48     // padded class count for layer-2 aggregate
#define KPAD 608   // 19 k-tiles of 32
#define GS 40      // LDS row stride in bf16 elems (80 B, 16B-aligned)

typedef __bf16 bf16x8 __attribute__((ext_vector_type(8)));
typedef __bf16 bf16x4 __attribute__((ext_vector_type(4)));
typedef float f32x16 __attribute__((ext_vector_type(16)));

__device__ __forceinline__ unsigned short f2bf(float f) {
    __bf16 b = (__bf16)f;
    return __builtin_bit_cast(unsigned short, b);
}
__device__ __forceinline__ float bf2f(unsigned short u) {
    return __uint_as_float((unsigned int)u << 16);
}
__device__ __forceinline__ float bflo(unsigned int u) { return __uint_as_float(u << 16); }
__device__ __forceinline__ float bfhi(unsigned int u) { return __uint_as_float(u & 0xffff0000u); }

// ---------------- CSR build ----------------

__global__ void k_hist(const int* __restrict__ dst, int* __restrict__ counts, int E) {
    int e = blockIdx.x * 256 + threadIdx.x;
    if (e < E) atomicAdd(&counts[dst[e]], 1);
}

__global__ void k_scan_a(const int* __restrict__ counts, int* __restrict__ row_ptr,
                         int* __restrict__ bsum, int n) {
    __shared__ int svals[256];
    __shared__ int soffs[256];
    int t = threadIdx.x;
    int base = blockIdx.x * 1024 + t * 4;
    int v[4];
    int s = 0;
#pragma unroll
    for (int j = 0; j < 4; ++j) {
        int idx = base + j;
        v[j] = (idx < n) ? counts[idx] : 0;
        s += v[j];
    }
    svals[t] = s;
    __syncthreads();
    if (t == 0) {
        int acc = 0;
        for (int i = 0; i < 256; ++i) { int tmp = svals[i]; soffs[i] = acc; acc += tmp; }
        bsum[blockIdx.x] = acc;
    }
    __syncthreads();
    int off = soffs[t];
#pragma unroll
    for (int j = 0; j < 4; ++j) {
        int idx = base + j;
        if (idx < n) row_ptr[idx] = off;
        off += v[j];
    }
}

__global__ void k_scan_b(int* __restrict__ bsum, int nb) {
    if (threadIdx.x == 0 && blockIdx.x == 0) {
        int acc = 0;
        for (int i = 0; i < nb; ++i) { int t = bsum[i]; bsum[i] = acc; acc += t; }
    }
}

__global__ void k_scan_c(int* __restrict__ row_ptr, const int* __restrict__ bsum, int n, int E) {
    int i = blockIdx.x * 256 + threadIdx.x;
    if (i < n) row_ptr[i] += bsum[i >> 10];
    if (i == 0) row_ptr[n] = E;
}

__global__ void k_dinv_cursor(const int* __restrict__ counts, const int* __restrict__ row_ptr,
                              float* __restrict__ dinv, int* __restrict__ cursor, int n) {
    int i = blockIdx.x * 256 + threadIdx.x;
    if (i < n) {
        dinv[i] = rsqrtf((float)(counts[i] + 1));
        cursor[i] = row_ptr[i];
    }
}

// fill per-edge meta: {src, norm = dinv[src]*dinv[dst]} grouped by dst (CSR order)
__global__ void k_fill(const int* __restrict__ src, const int* __restrict__ dst,
                       const float* __restrict__ dinv,
                       int* __restrict__ cursor, int2* __restrict__ meta, int E) {
    int e = blockIdx.x * 256 + threadIdx.x;
    if (e < E) {
        int s = src[e];
        int d = dst[e];
        int p = atomicAdd(&cursor[d], 1);
        float w = dinv[s] * dinv[d];
        meta[p] = make_int2(s, __float_as_int(w));
    }
}

// ---------------- W1 -> bf16 transposed+padded: W1T[n][k], n<128, k<608 ----------------

__global__ void k_prepW1(const float* __restrict__ W1, unsigned short* __restrict__ W1T) {
    int i = blockIdx.x * 256 + threadIdx.x;
    if (i >= GH * KPAD) return;
    int n = i / KPAD;
    int k = i - n * KPAD;
    float v = (k < GK) ? W1[(size_t)k * GH + n] : 0.f;
    W1T[i] = f2bf(v);
}

// ---------------- GEMM1 via MFMA bf16: X(M x 602) @ W1 -> Y bf16 (M x 128) ----------------

__global__ __launch_bounds__(256) void k_gemm1_mfma(const float* __restrict__ X,
                                                    const unsigned short* __restrict__ W1T,
                                                    unsigned short* __restrict__ Y, int M) {
    __shared__ __bf16 As[128 * GS];
    __shared__ __bf16 Bs[128 * GS];
    int tid = threadIdx.x;
    int lane = tid & 63;
    int w = tid >> 6;
    int row0 = blockIdx.x * 128;

    f32x16 acc[4];
#pragma unroll
    for (int c = 0; c < 4; ++c)
#pragma unroll
        for (int i = 0; i < 16; ++i) acc[c][i] = 0.f;

    int sr = tid >> 3;
    int sk = (tid & 7) * 4;
    int am = 32 * w + (lane & 31);
    int kh = (lane >> 5) * 8;
    int bn = lane & 31;

    for (int k0 = 0; k0 < KPAD; k0 += 32) {
#pragma unroll
        for (int p = 0; p < 4; ++p) {
            int r = sr + 32 * p;
            int gr = row0 + r;
            int gk = k0 + sk;
            float4 v = make_float4(0.f, 0.f, 0.f, 0.f);
            if (gr < M) {
                if (gk + 4 <= GK) {
                    v = *(const float4*)&X[(size_t)gr * GK + gk];
                } else {
                    float t0 = (gk + 0 < GK) ? X[(size_t)gr * GK + gk + 0] : 0.f;
                    float t1 = (gk + 1 < GK) ? X[(size_t)gr * GK + gk + 1] : 0.f;
                    float t2 = (gk + 2 < GK) ? X[(size_t)gr * GK + gk + 2] : 0.f;
                    float t3 = (gk + 3 < GK) ? X[(size_t)gr * GK + gk + 3] : 0.f;
                    v = make_float4(t0, t1, t2, t3);
                }
            }
            bf16x4 b4;
            b4[0] = (__bf16)v.x; b4[1] = (__bf16)v.y; b4[2] = (__bf16)v.z; b4[3] = (__bf16)v.w;
            *(bf16x4*)&As[r * GS + sk] = b4;
        }
#pragma unroll
        for (int s = 0; s < 2; ++s) {
            int slot = tid + 256 * s;
            int n = slot >> 2;
            int j = slot & 3;
            uint4 v = *(const uint4*)&W1T[(size_t)n * KPAD + k0 + 8 * j];
            *(uint4*)&Bs[n * GS + 8 * j] = v;
        }
        __syncthreads();
#pragma unroll
        for (int t = 0; t < 2; ++t) {
            bf16x8 af = *(const bf16x8*)&As[am * GS + 16 * t + kh];
#pragma unroll
            for (int c = 0; c < 4; ++c) {
                bf16x8 bf = *(const bf16x8*)&Bs[(32 * c + bn) * GS + 16 * t + kh];
                acc[c] = __builtin_amdgcn_mfma_f32_32x32x16_bf16(af, bf, acc[c], 0, 0, 0);
            }
        }
        __syncthreads();
    }
#pragma unroll
    for (int c = 0; c < 4; ++c) {
#pragma unroll
        for (int reg = 0; reg < 16; ++reg) {
            int rrow = (reg & 3) + 8 * (reg >> 2) + 4 * (lane >> 5);
            int grow = row0 + 32 * w + rrow;
            int gcol = 32 * c + (lane & 31);
            if (grow < M) Y[(size_t)grow * GH + gcol] = f2bf(acc[c][reg]);
        }
    }
}

// ---------------- layer-1 aggregate: 128-wide bf16 gather, unroll-4 MLP ----------------

__global__ __launch_bounds__(256) void k_agg1(const unsigned int* __restrict__ H,
                                              unsigned int* __restrict__ O,
                                              const int* __restrict__ row_ptr,
                                              const int2* __restrict__ meta,
                                              const float* __restrict__ dinv,
                                              const float* __restrict__ bias, int n) {
    int wv = threadIdx.x >> 6;
    int lane = threadIdx.x & 63;
    int d = blockIdx.x * 4 + wv;
    if (d >= n) return;
    float dd = dinv[d];
    int beg = row_ptr[d], end = row_ptr[d + 1];
    unsigned int v = H[(size_t)d * 64 + lane];
    float sw = dd * dd;
    float a0 = sw * bflo(v);
    float a1 = sw * bfhi(v);
    int e = beg;
    for (; e + 4 <= end; e += 4) {
        int2 m0 = meta[e + 0];
        int2 m1 = meta[e + 1];
        int2 m2 = meta[e + 2];
        int2 m3 = meta[e + 3];
        unsigned int u0 = H[(size_t)m0.x * 64 + lane];
        unsigned int u1 = H[(size_t)m1.x * 64 + lane];
        unsigned int u2 = H[(size_t)m2.x * 64 + lane];
        unsigned int u3 = H[(size_t)m3.x * 64 + lane];
        float w0 = __int_as_float(m0.y);
        float w1 = __int_as_float(m1.y);
        float w2 = __int_as_float(m2.y);
        float w3 = __int_as_float(m3.y);
        a0 = fmaf(w0, bflo(u0), a0); a1 = fmaf(w0, bfhi(u0), a1);
        a0 = fmaf(w1, bflo(u1), a0); a1 = fmaf(w1, bfhi(u1), a1);
        a0 = fmaf(w2, bflo(u2), a0); a1 = fmaf(w2, bfhi(u2), a1);
        a0 = fmaf(w3, bflo(u3), a0); a1 = fmaf(w3, bfhi(u3), a1);
    }
    for (; e < end; ++e) {
        int2 m = meta[e];
        unsigned int u = H[(size_t)m.x * 64 + lane];
        float w = __int_as_float(m.y);
        a0 = fmaf(w, bflo(u), a0);
        a1 = fmaf(w, bfhi(u), a1);
    }
    a0 = fmaxf(a0 + bias[2 * lane], 0.f);
    a1 = fmaxf(a1 + bias[2 * lane + 1], 0.f);
    O[(size_t)d * 64 + lane] = (unsigned int)f2bf(a0) | ((unsigned int)f2bf(a1) << 16);
}

// ---------------- layer-2 transform first: G = relu(H1) @ W2, bf16 out, padded to 48 ----------------
// 2 rows per thread (W2 LDS reads amortized), 512 rows per block.

__global__ __launch_bounds__(256) void k_gemm2t(const unsigned int* __restrict__ Hb,
                                                const float* __restrict__ W2,
                                                unsigned short* __restrict__ G, int n) {
    __shared__ float ws[128][GCP];
    for (int i = threadIdx.x; i < 128 * GCP; i += 256) {
        int k = i / GCP;
        int c = i - k * GCP;
        ws[k][c] = (c < GC) ? W2[k * GC + c] : 0.f;
    }
    __syncthreads();
    int r0 = blockIdx.x * 512 + threadIdx.x;
    int r1 = r0 + 256;
    bool v0 = r0 < n, v1 = r1 < n;
    float acc0[GCP], acc1[GCP];
#pragma unroll
    for (int c = 0; c < GCP; ++c) { acc0[c] = 0.f; acc1[c] = 0.f; }
    const uint2* h0 = (const uint2*)(Hb + (size_t)(v0 ? r0 : 0) * 64);
    const uint2* h1 = (const uint2*)(Hb + (size_t)(v1 ? r1 : 0) * 64);
    for (int q = 0; q < 32; ++q) {
        uint2 ua = h0[q];
        uint2 ub = h1[q];
        float va[4] = {bflo(ua.x), bfhi(ua.x), bflo(ua.y), bfhi(ua.y)};
        float vb[4] = {bflo(ub.x), bfhi(ub.x), bflo(ub.y), bfhi(ub.y)};
#pragma unroll
        for (int j = 0; j < 4; ++j) {
            int k = 4 * q + j;
#pragma unroll
            for (int cq = 0; cq < GCP / 4; ++cq) {
                float4 wv = *(const float4*)&ws[k][4 * cq];
                acc0[4 * cq + 0] = fmaf(va[j], wv.x, acc0[4 * cq + 0]);
                acc0[4 * cq + 1] = fmaf(va[j], wv.y, acc0[4 * cq + 1]);
                acc0[4 * cq + 2] = fmaf(va[j], wv.z, acc0[4 * cq + 2]);
                acc0[4 * cq + 3] = fmaf(va[j], wv.w, acc0[4 * cq + 3]);
                acc1[4 * cq + 0] = fmaf(vb[j], wv.x, acc1[4 * cq + 0]);
                acc1[4 * cq + 1] = fmaf(vb[j], wv.y, acc1[4 * cq + 1]);
                acc1[4 * cq + 2] = fmaf(vb[j], wv.z, acc1[4 * cq + 2]);
                acc1[4 * cq + 3] = fmaf(vb[j], wv.w, acc1[4 * cq + 3]);
            }
        }
    }
    if (v0) {
#pragma unroll
        for (int c = 0; c < GCP; ++c) G[(size_t)r0 * GCP + c] = f2bf(acc0[c]);
    }
    if (v1) {
#pragma unroll
        for (int c = 0; c < GCP; ++c) G[(size_t)r1 * GCP + c] = f2bf(acc1[c]);
    }
}

// ---------------- layer-2 aggregate at width 48 + bias + log_softmax, write d_out ----------------

__global__ __launch_bounds__(256) void k_agg2(const unsigned short* __restrict__ G,
                                              float* __restrict__ out,
                                              const int* __restrict__ row_ptr,
                                              const int2* __restrict__ meta,
                                              const float* __restrict__ dinv,
                                              const float* __restrict__ b2, int n) {
    int wv = threadIdx.x >> 6;
    int lane = threadIdx.x & 63;
    int gl = (lane < GCP) ? lane : (GCP - 1);  // lanes 48-63 duplicate col 47 (zero pad)
    int d = blockIdx.x * 4 + wv;
    if (d >= n) return;
    float dd = dinv[d];
    int beg = row_ptr[d], end = row_ptr[d + 1];
    float a = dd * dd * bf2f(G[(size_t)d * GCP + gl]);
    int e = beg;
    for (; e + 4 <= end; e += 4) {
        int2 m0 = meta[e + 0];
        int2 m1 = meta[e + 1];
        int2 m2 = meta[e + 2];
        int2 m3 = meta[e + 3];
        unsigned short u0 = G[(size_t)m0.x * GCP + gl];
        unsigned short u1 = G[(size_t)m1.x * GCP + gl];
        unsigned short u2 = G[(size_t)m2.x * GCP + gl];
        unsigned short u3 = G[(size_t)m3.x * GCP + gl];
        a = fmaf(__int_as_float(m0.y), bf2f(u0), a);
        a = fmaf(__int_as_float(m1.y), bf2f(u1), a);
        a = fmaf(__int_as_float(m2.y), bf2f(u2), a);
        a = fmaf(__int_as_float(m3.y), bf2f(u3), a);
    }
    for (; e < end; ++e) {
        int2 m = meta[e];
        unsigned short u = G[(size_t)m.x * GCP + gl];
        a = fmaf(__int_as_float(m.y), bf2f(u), a);
    }
    // fused bias + log_softmax over 41 classes spread across lanes
    float logit = (lane < GC) ? (a + b2[lane]) : -INFINITY;
    float mx = logit;
#pragma unroll
    for (int off = 32; off; off >>= 1) mx = fmaxf(mx, __shfl_xor(mx, off));
    float ex = (lane < GC) ? __expf(logit - mx) : 0.f;
    float sm = ex;
#pragma unroll
    for (int off = 32; off; off >>= 1) sm += __shfl_xor(sm, off);
    if (lane < GC) out[(size_t)d * GC + lane] = logit - mx - __logf(sm);
}

// ---------------- launch ----------------

static inline size_t alignup256(size_t x) { return (x + 255) & ~(size_t)255; }

extern "C" void kernel_launch(void* const* d_in, const int* in_sizes, int n_in,
                              void* d_out, int out_size, void* d_ws, size_t ws_size,
                              hipStream_t stream) {
    const float* x  = (const float*)d_in[0];
    const int*   ei = (const int*)d_in[1];
    const float* W1 = (const float*)d_in[2];
    const float* b1 = (const float*)d_in[3];
    const float* W2 = (const float*)d_in[4];
    const float* b2 = (const float*)d_in[5];
    float* out = (float*)d_out;

    const int n = in_sizes[0] / GK;   // 100000
    const int E = in_sizes[1] / 2;    // 1600000
    const int* src = ei;
    const int* dst = ei + E;

    char* w = (char*)d_ws;
    char* p;
    p = w; w += alignup256((size_t)n * 4);            float* dinv  = (float*)p;
    p = w; w += alignup256((size_t)n * 4);            int* counts  = (int*)p;
    p = w; w += alignup256((size_t)n * 4);            int* cursor  = (int*)p;
    p = w; w += alignup256((size_t)(n + 1) * 4);      int* row_ptr = (int*)p;
    p = w; w += alignup256(1024 * 4);                 int* bsum    = (int*)p;
    p = w; w += alignup256((size_t)E * 8);            int2* meta   = (int2*)p;
    p = w; w += alignup256((size_t)GH * KPAD * 2);    unsigned short* W1T = (unsigned short*)p;
    p = w; w += alignup256((size_t)n * GH * 2);       unsigned short* bufA = (unsigned short*)p; // bf16 H1
    p = w; w += alignup256((size_t)n * GH * 2);       unsigned short* bufB = (unsigned short*)p; // bf16 relu(agg1)
    p = w; w += alignup256((size_t)n * GCP * 2);      unsigned short* G    = (unsigned short*)p; // bf16 H1relu@W2

    hipMemsetAsync(counts, 0, (size_t)n * 4, stream);

    int gE = (E + 255) / 256;
    int gN = (n + 255) / 256;
    int nb = (n + 1023) / 1024;

    k_hist<<<gE, 256, 0, stream>>>(dst, counts, E);
    k_scan_a<<<nb, 256, 0, stream>>>(counts, row_ptr, bsum, n);
    k_scan_b<<<1, 64, 0, stream>>>(bsum, nb);
    k_scan_c<<<gN, 256, 0, stream>>>(row_ptr, bsum, n, E);
    k_dinv_cursor<<<gN, 256, 0, stream>>>(counts, row_ptr, dinv, cursor, n);
    k_fill<<<gE, 256, 0, stream>>>(src, dst, dinv, cursor, meta, E);

    k_prepW1<<<(GH * KPAD + 255) / 256, 256, 0, stream>>>(W1, W1T);
    k_gemm1_mfma<<<(n + 127) / 128, 256, 0, stream>>>(x, W1T, bufA, n);
    k_agg1<<<(n + 3) / 4, 256, 0, stream>>>((const unsigned int*)bufA, (unsigned int*)bufB,
                                            row_ptr, meta, dinv, b1, n);
    k_gemm2t<<<(n + 511) / 512, 256, 0, stream>>>((const unsigned int*)bufB, W2, G, n);
    k_agg2<<<(n + 3) / 4, 256, 0, stream>>>(G, out, row_ptr, meta, dinv, b2, n);
}

// Round 4
// 726.733 us; speedup vs baseline: 1.5090x; 1.0041x over previous
//
#include <hip/hip_runtime.h>
#include <math.h>

#define GK 602
#define GH 128
#define GC 41
#define GCP 48     // padded class count for layer-2 aggregate
#define KPAD 608   // 19 k-tiles of 32
#define GS 40      // LDS row stride in bf16 elems (80 B, 16B-aligned)

typedef __bf16 bf16x8 __attribute__((ext_vector_type(8)));
typedef __bf16 bf16x4 __attribute__((ext_vector_type(4)));
typedef float f32x16 __attribute__((ext_vector_type(16)));

__device__ __forceinline__ unsigned short f2bf(float f) {
    __bf16 b = (__bf16)f;
    return __builtin_bit_cast(unsigned short, b);
}
__device__ __forceinline__ float bf2f(unsigned short u) {
    return __uint_as_float((unsigned int)u << 16);
}
__device__ __forceinline__ float bflo(unsigned int u) { return __uint_as_float(u << 16); }
__device__ __forceinline__ float bfhi(unsigned int u) { return __uint_as_float(u & 0xffff0000u); }

// ---------------- CSR build ----------------

__global__ void k_hist(const int* __restrict__ dst, int* __restrict__ counts, int E) {
    int e = blockIdx.x * 256 + threadIdx.x;
    if (e < E) atomicAdd(&counts[dst[e]], 1);
}

// exclusive scan of counts -> row_ptr, 1024 elems/block, shuffle-based
__global__ void k_scan_a(const int* __restrict__ counts, int* __restrict__ row_ptr,
                         int* __restrict__ bsum, int n) {
    __shared__ int wsum[4];
    int t = threadIdx.x;
    int lane = t & 63;
    int wv = t >> 6;
    int base = blockIdx.x * 1024 + t * 4;
    int v[4];
    int s = 0;
#pragma unroll
    for (int j = 0; j < 4; ++j) {
        int idx = base + j;
        v[j] = (idx < n) ? counts[idx] : 0;
        s += v[j];
    }
    int incl = s;
#pragma unroll
    for (int o = 1; o < 64; o <<= 1) {
        int x = __shfl_up(incl, o);
        if (lane >= o) incl += x;
    }
    if (lane == 63) wsum[wv] = incl;
    __syncthreads();
    int woff = 0;
#pragma unroll
    for (int i = 0; i < 3; ++i) woff += (i < wv) ? wsum[i] : 0;
    if (t == 255) bsum[blockIdx.x] = woff + incl;
    int off = woff + incl - s;  // exclusive prefix for this thread's 4 elems
#pragma unroll
    for (int j = 0; j < 4; ++j) {
        int idx = base + j;
        if (idx < n) row_ptr[idx] = off;
        off += v[j];
    }
}

// single-block exclusive scan of bsum (nb <= 256)
__global__ void k_scan_b(int* __restrict__ bsum, int nb) {
    __shared__ int sh[256];
    int t = threadIdx.x;
    int v = (t < nb) ? bsum[t] : 0;
    sh[t] = v;
    __syncthreads();
    for (int o = 1; o < 256; o <<= 1) {
        int x = (t >= o) ? sh[t - o] : 0;
        __syncthreads();
        sh[t] += x;
        __syncthreads();
    }
    if (t < nb) bsum[t] = sh[t] - v;
}

// finalize row_ptr, init cursor, compute dinv (fused)
__global__ void k_scan_c(int* __restrict__ row_ptr, const int* __restrict__ bsum,
                         const int* __restrict__ counts, float* __restrict__ dinv,
                         int* __restrict__ cursor, int n, int E) {
    int i = blockIdx.x * 256 + threadIdx.x;
    if (i < n) {
        int rp = row_ptr[i] + bsum[i >> 10];
        row_ptr[i] = rp;
        cursor[i] = rp;
        dinv[i] = rsqrtf((float)(counts[i] + 1));  // +1 self-loop
    }
    if (i == 0) row_ptr[n] = E;
}

// fill per-edge meta: {src, norm = dinv[src]*dinv[dst]} grouped by dst (CSR order)
__global__ void k_fill(const int* __restrict__ src, const int* __restrict__ dst,
                       const float* __restrict__ dinv,
                       int* __restrict__ cursor, int2* __restrict__ meta, int E) {
    int e = blockIdx.x * 256 + threadIdx.x;
    if (e < E) {
        int s = src[e];
        int d = dst[e];
        int p = atomicAdd(&cursor[d], 1);
        float w = dinv[s] * dinv[d];
        meta[p] = make_int2(s, __float_as_int(w));
    }
}

// ---------------- W1 -> bf16 transposed+padded: W1T[n][k], n<128, k<608 ----------------

__global__ void k_prepW1(const float* __restrict__ W1, unsigned short* __restrict__ W1T) {
    int i = blockIdx.x * 256 + threadIdx.x;
    if (i >= GH * KPAD) return;
    int n = i / KPAD;
    int k = i - n * KPAD;
    float v = (k < GK) ? W1[(size_t)k * GH + n] : 0.f;
    W1T[i] = f2bf(v);
}

// ---------------- GEMM1 via MFMA bf16: X(M x 602) @ W1 -> Y bf16 (M x 128) ----------------
// A-fragments loaded DIRECTLY from global (no LDS staging, convert in regs);
// B (W1T) k-tiles double-buffered in LDS; one barrier per k-iter.

struct AF { float4 v0, v1, v2, v3; };

__device__ __forceinline__ AF loadA(const float* __restrict__ xr, int kb, bool tail) {
    AF r;
    if (!tail) {
        r.v0 = *(const float4*)(xr + kb);
        r.v1 = *(const float4*)(xr + kb + 4);
        r.v2 = *(const float4*)(xr + kb + 16);
        r.v3 = *(const float4*)(xr + kb + 20);
    } else {
        float tv[8], tw[8];
#pragma unroll
        for (int j = 0; j < 8; ++j) {
            int k0_ = kb + j;
            int k1_ = kb + 16 + j;
            tv[j] = (k0_ < GK) ? xr[k0_] : 0.f;
            tw[j] = (k1_ < GK) ? xr[k1_] : 0.f;
        }
        r.v0 = make_float4(tv[0], tv[1], tv[2], tv[3]);
        r.v1 = make_float4(tv[4], tv[5], tv[6], tv[7]);
        r.v2 = make_float4(tw[0], tw[1], tw[2], tw[3]);
        r.v3 = make_float4(tw[4], tw[5], tw[6], tw[7]);
    }
    return r;
}

__device__ __forceinline__ bf16x8 cvt8(float4 a, float4 b) {
    bf16x8 r;
    r[0] = (__bf16)a.x; r[1] = (__bf16)a.y; r[2] = (__bf16)a.z; r[3] = (__bf16)a.w;
    r[4] = (__bf16)b.x; r[5] = (__bf16)b.y; r[6] = (__bf16)b.z; r[7] = (__bf16)b.w;
    return r;
}

__device__ __forceinline__ void stageB(const unsigned short* __restrict__ W1T,
                                       __bf16* __restrict__ Bsb, int tid, int k0) {
#pragma unroll
    for (int s = 0; s < 2; ++s) {
        int slot = tid + 256 * s;
        int n = slot >> 2;
        int j = slot & 3;
        uint4 v = *(const uint4*)&W1T[(size_t)n * KPAD + k0 + 8 * j];
        *(uint4*)&Bsb[n * GS + 8 * j] = v;
    }
}

__global__ __launch_bounds__(256) void k_gemm1_mfma(const float* __restrict__ X,
                                                    const unsigned short* __restrict__ W1T,
                                                    unsigned short* __restrict__ Y, int M) {
    __shared__ __bf16 Bs[2][128 * GS];
    int tid = threadIdx.x;
    int lane = tid & 63;
    int w = tid >> 6;
    int row0 = blockIdx.x * 128;
    int amr = 32 * w + (lane & 31);
    int grow_base = row0 + amr;
    int arow = (grow_base < M) ? grow_base : (M - 1);  // clamp OOB rows (not stored)
    const float* xr = X + (size_t)arow * GK;
    int kh = (lane >> 5) * 8;
    int bn = lane & 31;

    f32x16 acc[4];
#pragma unroll
    for (int c = 0; c < 4; ++c)
#pragma unroll
        for (int i = 0; i < 16; ++i) acc[c][i] = 0.f;

    stageB(W1T, Bs[0], tid, 0);
    AF a = loadA(xr, kh, false);
    __syncthreads();

    int buf = 0;
    for (int it = 0; it < 19; ++it) {
        AF an;
        if (it < 18) {
            stageB(W1T, Bs[buf ^ 1], tid, 32 * (it + 1));
            an = loadA(xr, kh + 32 * (it + 1), it == 17);
        }
        bf16x8 af0 = cvt8(a.v0, a.v1);
        bf16x8 af1 = cvt8(a.v2, a.v3);
#pragma unroll
        for (int c = 0; c < 4; ++c) {
            bf16x8 b0 = *(const bf16x8*)&Bs[buf][(32 * c + bn) * GS + kh];
            acc[c] = __builtin_amdgcn_mfma_f32_32x32x16_bf16(af0, b0, acc[c], 0, 0, 0);
        }
#pragma unroll
        for (int c = 0; c < 4; ++c) {
            bf16x8 b1 = *(const bf16x8*)&Bs[buf][(32 * c + bn) * GS + 16 + kh];
            acc[c] = __builtin_amdgcn_mfma_f32_32x32x16_bf16(af1, b1, acc[c], 0, 0, 0);
        }
        __syncthreads();
        buf ^= 1;
        a = an;
    }
    // epilogue: C/D layout col=lane&31, row=(reg&3)+8*(reg>>2)+4*(lane>>5)
#pragma unroll
    for (int c = 0; c < 4; ++c) {
#pragma unroll
        for (int reg = 0; reg < 16; ++reg) {
            int rrow = (reg & 3) + 8 * (reg >> 2) + 4 * (lane >> 5);
            int grow = row0 + 32 * w + rrow;
            int gcol = 32 * c + (lane & 31);
            if (grow < M) Y[(size_t)grow * GH + gcol] = f2bf(acc[c][reg]);
        }
    }
}

// ---------------- layer-1 aggregate: 128-wide bf16 gather, unroll-8 MLP ----------------

__global__ __launch_bounds__(256) void k_agg1(const unsigned int* __restrict__ H,
                                              unsigned int* __restrict__ O,
                                              const int* __restrict__ row_ptr,
                                              const int2* __restrict__ meta,
                                              const float* __restrict__ dinv,
                                              const float* __restrict__ bias, int n) {
    int wv = threadIdx.x >> 6;
    int lane = threadIdx.x & 63;
    int d = blockIdx.x * 4 + wv;
    if (d >= n) return;
    float dd = dinv[d];
    int beg = row_ptr[d], end = row_ptr[d + 1];
    unsigned int v = H[(size_t)d * 64 + lane];
    float sw = dd * dd;
    float a0 = sw * bflo(v);
    float a1 = sw * bfhi(v);
    int e = beg;
    for (; e + 8 <= end; e += 8) {
        int2 m[8];
        unsigned int u[8];
#pragma unroll
        for (int j = 0; j < 8; ++j) m[j] = meta[e + j];
#pragma unroll
        for (int j = 0; j < 8; ++j) u[j] = H[(size_t)m[j].x * 64 + lane];
#pragma unroll
        for (int j = 0; j < 8; ++j) {
            float wj = __int_as_float(m[j].y);
            a0 = fmaf(wj, bflo(u[j]), a0);
            a1 = fmaf(wj, bfhi(u[j]), a1);
        }
    }
    if (e + 4 <= end) {
        int2 m[4];
        unsigned int u[4];
#pragma unroll
        for (int j = 0; j < 4; ++j) m[j] = meta[e + j];
#pragma unroll
        for (int j = 0; j < 4; ++j) u[j] = H[(size_t)m[j].x * 64 + lane];
#pragma unroll
        for (int j = 0; j < 4; ++j) {
            float wj = __int_as_float(m[j].y);
            a0 = fmaf(wj, bflo(u[j]), a0);
            a1 = fmaf(wj, bfhi(u[j]), a1);
        }
        e += 4;
    }
    for (; e < end; ++e) {
        int2 m = meta[e];
        unsigned int u = H[(size_t)m.x * 64 + lane];
        float wj = __int_as_float(m.y);
        a0 = fmaf(wj, bflo(u), a0);
        a1 = fmaf(wj, bfhi(u), a1);
    }
    a0 = fmaxf(a0 + bias[2 * lane], 0.f);
    a1 = fmaxf(a1 + bias[2 * lane + 1], 0.f);
    O[(size_t)d * 64 + lane] = (unsigned int)f2bf(a0) | ((unsigned int)f2bf(a1) << 16);
}

// ---------------- layer-2 transform first: G = relu(H1) @ W2, bf16 out, padded to 48 ----------------

__global__ __launch_bounds__(256) void k_gemm2t(const unsigned int* __restrict__ Hb,
                                                const float* __restrict__ W2,
                                                unsigned short* __restrict__ G, int n) {
    __shared__ float ws[128][GCP];
    for (int i = threadIdx.x; i < 128 * GCP; i += 256) {
        int k = i / GCP;
        int c = i - k * GCP;
        ws[k][c] = (c < GC) ? W2[k * GC + c] : 0.f;
    }
    __syncthreads();
    int r0 = blockIdx.x * 512 + threadIdx.x;
    int r1 = r0 + 256;
    bool v0 = r0 < n, v1 = r1 < n;
    float acc0[GCP], acc1[GCP];
#pragma unroll
    for (int c = 0; c < GCP; ++c) { acc0[c] = 0.f; acc1[c] = 0.f; }
    const uint2* h0 = (const uint2*)(Hb + (size_t)(v0 ? r0 : 0) * 64);
    const uint2* h1 = (const uint2*)(Hb + (size_t)(v1 ? r1 : 0) * 64);
    for (int q = 0; q < 32; ++q) {
        uint2 ua = h0[q];
        uint2 ub = h1[q];
        float va[4] = {bflo(ua.x), bfhi(ua.x), bflo(ua.y), bfhi(ua.y)};
        float vb[4] = {bflo(ub.x), bfhi(ub.x), bflo(ub.y), bfhi(ub.y)};
#pragma unroll
        for (int j = 0; j < 4; ++j) {
            int k = 4 * q + j;
#pragma unroll
            for (int cq = 0; cq < GCP / 4; ++cq) {
                float4 wv = *(const float4*)&ws[k][4 * cq];
                acc0[4 * cq + 0] = fmaf(va[j], wv.x, acc0[4 * cq + 0]);
                acc0[4 * cq + 1] = fmaf(va[j], wv.y, acc0[4 * cq + 1]);
                acc0[4 * cq + 2] = fmaf(va[j], wv.z, acc0[4 * cq + 2]);
                acc0[4 * cq + 3] = fmaf(va[j], wv.w, acc0[4 * cq + 3]);
                acc1[4 * cq + 0] = fmaf(vb[j], wv.x, acc1[4 * cq + 0]);
                acc1[4 * cq + 1] = fmaf(vb[j], wv.y, acc1[4 * cq + 1]);
                acc1[4 * cq + 2] = fmaf(vb[j], wv.z, acc1[4 * cq + 2]);
                acc1[4 * cq + 3] = fmaf(vb[j], wv.w, acc1[4 * cq + 3]);
            }
        }
    }
    if (v0) {
#pragma unroll
        for (int c = 0; c < GCP; ++c) G[(size_t)r0 * GCP + c] = f2bf(acc0[c]);
    }
    if (v1) {
#pragma unroll
        for (int c = 0; c < GCP; ++c) G[(size_t)r1 * GCP + c] = f2bf(acc1[c]);
    }
}

// ---------------- layer-2 aggregate at width 48 + bias + log_softmax, write d_out ----------------

__global__ __launch_bounds__(256) void k_agg2(const unsigned short* __restrict__ G,
                                              float* __restrict__ out,
                                              const int* __restrict__ row_ptr,
                                              const int2* __restrict__ meta,
                                              const float* __restrict__ dinv,
                                              const float* __restrict__ b2, int n) {
    int wv = threadIdx.x >> 6;
    int lane = threadIdx.x & 63;
    int gl = (lane < GCP) ? lane : (GCP - 1);
    int d = blockIdx.x * 4 + wv;
    if (d >= n) return;
    float dd = dinv[d];
    int beg = row_ptr[d], end = row_ptr[d + 1];
    float a = dd * dd * bf2f(G[(size_t)d * GCP + gl]);
    int e = beg;
    for (; e + 8 <= end; e += 8) {
        int2 m[8];
        unsigned short u[8];
#pragma unroll
        for (int j = 0; j < 8; ++j) m[j] = meta[e + j];
#pragma unroll
        for (int j = 0; j < 8; ++j) u[j] = G[(size_t)m[j].x * GCP + gl];
#pragma unroll
        for (int j = 0; j < 8; ++j) a = fmaf(__int_as_float(m[j].y), bf2f(u[j]), a);
    }
    if (e + 4 <= end) {
        int2 m[4];
        unsigned short u[4];
#pragma unroll
        for (int j = 0; j < 4; ++j) m[j] = meta[e + j];
#pragma unroll
        for (int j = 0; j < 4; ++j) u[j] = G[(size_t)m[j].x * GCP + gl];
#pragma unroll
        for (int j = 0; j < 4; ++j) a = fmaf(__int_as_float(m[j].y), bf2f(u[j]), a);
        e += 4;
    }
    for (; e < end; ++e) {
        int2 m = meta[e];
        a = fmaf(__int_as_float(m.y), bf2f(G[(size_t)m.x * GCP + gl]), a);
    }
    float logit = (lane < GC) ? (a + b2[lane]) : -INFINITY;
    float mx = logit;
#pragma unroll
    for (int off = 32; off; off >>= 1) mx = fmaxf(mx, __shfl_xor(mx, off));
    float ex = (lane < GC) ? __expf(logit - mx) : 0.f;
    float sm = ex;
#pragma unroll
    for (int off = 32; off; off >>= 1) sm += __shfl_xor(sm, off);
    if (lane < GC) out[(size_t)d * GC + lane] = logit - mx - __logf(sm);
}

// ---------------- launch ----------------

static inline size_t alignup256(size_t x) { return (x + 255) & ~(size_t)255; }

extern "C" void kernel_launch(void* const* d_in, const int* in_sizes, int n_in,
                              void* d_out, int out_size, void* d_ws, size_t ws_size,
                              hipStream_t stream) {
    const float* x  = (const float*)d_in[0];
    const int*   ei = (const int*)d_in[1];
    const float* W1 = (const float*)d_in[2];
    const float* b1 = (const float*)d_in[3];
    const float* W2 = (const float*)d_in[4];
    const float* b2 = (const float*)d_in[5];
    float* out = (float*)d_out;

    const int n = in_sizes[0] / GK;   // 100000
    const int E = in_sizes[1] / 2;    // 1600000
    const int* src = ei;
    const int* dst = ei + E;

    char* w = (char*)d_ws;
    char* p;
    p = w; w += alignup256((size_t)n * 4);            float* dinv  = (float*)p;
    p = w; w += alignup256((size_t)n * 4);            int* counts  = (int*)p;
    p = w; w += alignup256((size_t)n * 4);            int* cursor  = (int*)p;
    p = w; w += alignup256((size_t)(n + 1) * 4);      int* row_ptr = (int*)p;
    p = w; w += alignup256(1024 * 4);                 int* bsum    = (int*)p;
    p = w; w += alignup256((size_t)E * 8);            int2* meta   = (int2*)p;
    p = w; w += alignup256((size_t)GH * KPAD * 2);    unsigned short* W1T = (unsigned short*)p;
    p = w; w += alignup256((size_t)n * GH * 2);       unsigned short* bufA = (unsigned short*)p; // bf16 H1
    p = w; w += alignup256((size_t)n * GH * 2);       unsigned short* bufB = (unsigned short*)p; // bf16 relu(agg1)
    p = w; w += alignup256((size_t)n * GCP * 2);      unsigned short* G    = (unsigned short*)p; // bf16 H1relu@W2

    hipMemsetAsync(counts, 0, (size_t)n * 4, stream);

    int gE = (E + 255) / 256;
    int gN = (n + 255) / 256;
    int nb = (n + 1023) / 1024;

    k_hist<<<gE, 256, 0, stream>>>(dst, counts, E);
    k_scan_a<<<nb, 256, 0, stream>>>(counts, row_ptr, bsum, n);
    k_scan_b<<<1, 256, 0, stream>>>(bsum, nb);
    k_scan_c<<<gN, 256, 0, stream>>>(row_ptr, bsum, counts, dinv, cursor, n, E);
    k_fill<<<gE, 256, 0, stream>>>(src, dst, dinv, cursor, meta, E);

    k_prepW1<<<(GH * KPAD + 255) / 256, 256, 0, stream>>>(W1, W1T);
    k_gemm1_mfma<<<(n + 127) / 128, 256, 0, stream>>>(x, W1T, bufA, n);
    k_agg1<<<(n + 3) / 4, 256, 0, stream>>>((const unsigned int*)bufA, (unsigned int*)bufB,
                                            row_ptr, meta, dinv, b1, n);
    k_gemm2t<<<(n + 511) / 512, 256, 0, stream>>>((const unsigned int*)bufB, W2, G, n);
    k_agg2<<<(n + 3) / 4, 256, 0, stream>>>(G, out, row_ptr, meta, dinv, b2, n);
}